// Round 1
// baseline (195.654 us; speedup 1.0000x reference)
//
#include <hip/hip_runtime.h>
#include <math.h>

// Problem constants (from reference setup_inputs): keypoints [32, 8192, 128] fp32
#define B 32
#define N 8192
#define D 128
#define SCALE_PARAM 1e-9f

// Kernel 1: grid-stride-free tiled reduction.
// Grid = (B*N)/ROWS_PER_BLOCK = 262144/128 = 2048 blocks, 256 threads.
// Each block handles 128 consecutive rows (all within one b since 8192%128==0).
// Thread t: d-quad d4 = t&31 (float4 column), rowgroup rg = t>>5 (8 rows/iter).
__global__ __launch_bounds__(256) void partial_kernel(
    const float* __restrict__ x,
    float* __restrict__ s_out,    // [B*D] accumulated via atomics
    float* __restrict__ ssq_out)  // [1]
{
    __shared__ float lds_s[8][D];   // per-rowgroup partial d-sums
    __shared__ float lds_ssq[4];    // per-wave sum-of-squares

    const int t  = threadIdx.x;
    const int d4 = t & 31;   // which float4 within the 128-float row
    const int rg = t >> 5;   // 0..7

    const long long row_base = (long long)blockIdx.x * 128;
    const int b = (int)(row_base >> 13);   // row / 8192

    const float4* __restrict__ x4 = (const float4*)x;

    float4 acc = make_float4(0.f, 0.f, 0.f, 0.f);
    float ssq = 0.f;

    #pragma unroll
    for (int it = 0; it < 16; ++it) {
        const long long row = row_base + it * 8 + rg;
        const float4 v = x4[row * (D / 4) + d4];
        acc.x += v.x; acc.y += v.y; acc.z += v.z; acc.w += v.w;
        ssq += v.x * v.x + v.y * v.y + v.z * v.z + v.w * v.w;
    }

    // Stage per-thread d-quad sums to LDS
    lds_s[rg][d4 * 4 + 0] = acc.x;
    lds_s[rg][d4 * 4 + 1] = acc.y;
    lds_s[rg][d4 * 4 + 2] = acc.z;
    lds_s[rg][d4 * 4 + 3] = acc.w;

    // Wave-64 shuffle reduction of ssq, then one slot per wave
    #pragma unroll
    for (int off = 32; off > 0; off >>= 1)
        ssq += __shfl_down(ssq, off);
    if ((t & 63) == 0) lds_ssq[t >> 6] = ssq;

    __syncthreads();

    // Threads 0..127: combine 8 rowgroups for their d, one atomic per d
    if (t < D) {
        float sd = 0.f;
        #pragma unroll
        for (int r = 0; r < 8; ++r) sd += lds_s[r][t];
        atomicAdd(&s_out[b * D + t], sd);
    }
    if (t == 0) {
        atomicAdd(ssq_out, lds_ssq[0] + lds_ssq[1] + lds_ssq[2] + lds_ssq[3]);
    }
}

// Kernel 2: finalize. sum(s^2) over 4096 values, combine with sum_sq, exp.
__global__ __launch_bounds__(256) void finalize_kernel(
    const float* __restrict__ s,
    const float* __restrict__ ssq,
    float* __restrict__ out)
{
    __shared__ float lds[4];
    const int t = threadIdx.x;

    float acc = 0.f;
    for (int i = t; i < B * D; i += 256) {
        const float v = s[i];
        acc += v * v;
    }
    #pragma unroll
    for (int off = 32; off > 0; off >>= 1)
        acc += __shfl_down(acc, off);
    if ((t & 63) == 0) lds[t >> 6] = acc;
    __syncthreads();

    if (t == 0) {
        const float sum_s2 = lds[0] + lds[1] + lds[2] + lds[3];
        const float sum_sq = ssq[0];
        const float total  = 2.0f * (float)N * sum_sq - 2.0f * sum_s2;
        const float sep    = total / ((float)B * (float)N * (float)D);
        out[0] = expf(-SCALE_PARAM * sep);
    }
}

extern "C" void kernel_launch(void* const* d_in, const int* in_sizes, int n_in,
                              void* d_out, int out_size, void* d_ws, size_t ws_size,
                              hipStream_t stream) {
    const float* x = (const float*)d_in[0];
    float* out = (float*)d_out;

    float* s_ws   = (float*)d_ws;        // B*D floats
    float* ssq_ws = s_ws + B * D;        // 1 float

    // Workspace is poisoned 0xAA before every launch — zero what we accumulate into.
    hipMemsetAsync(d_ws, 0, (B * D + 1) * sizeof(float), stream);

    const int total_rows = B * N;          // 262144
    const int blocks = total_rows / 128;   // 2048
    partial_kernel<<<blocks, 256, 0, stream>>>(x, s_ws, ssq_ws);
    finalize_kernel<<<1, 256, 0, stream>>>(s_ws, ssq_ws, out);
}

// Round 2
// 186.052 us; speedup vs baseline: 1.0516x; 1.0516x over previous
//
#include <hip/hip_runtime.h>
#include <math.h>

// Problem constants (from reference setup_inputs): keypoints [32, 8192, 128] fp32
#define B 32
#define N 8192
#define D 128
#define SCALE_PARAM 1e-9f

#define ROWS_PER_BLOCK 128
#define NBLOCKS ((B * N) / ROWS_PER_BLOCK)   // 2048

typedef float __attribute__((ext_vector_type(4))) f32x4;

// Kernel 1: each block reduces 128 consecutive rows (within one b; 8192%128==0).
// Writes 128 per-d partial sums + 1 sum-of-squares partial, NON-atomically.
// Thread t: d-quad d4 = t&31 (float4 column), rowgroup rg = t>>5 (8 rows/iter).
__global__ __launch_bounds__(256) void partial_kernel(
    const float* __restrict__ x,
    float* __restrict__ P,     // [NBLOCKS][D] per-block d-sums
    float* __restrict__ SS)    // [NBLOCKS] per-block sum(x^2)
{
    __shared__ f32x4 lds_s4[8][32];   // [rowgroup][d-quad]
    __shared__ float lds_ssq[4];

    const int t  = threadIdx.x;
    const int d4 = t & 31;
    const int rg = t >> 5;

    const int row_base = blockIdx.x * ROWS_PER_BLOCK;
    const f32x4* __restrict__ x4 = (const f32x4*)x;

    f32x4 acc = {0.f, 0.f, 0.f, 0.f};
    float ssq = 0.f;

    #pragma unroll
    for (int it = 0; it < 16; ++it) {
        const int row = row_base + it * 8 + rg;
        const f32x4 v = __builtin_nontemporal_load(&x4[row * (D / 4) + d4]);
        acc += v;
        ssq += v.x * v.x + v.y * v.y + v.z * v.z + v.w * v.w;
    }

    lds_s4[rg][d4] = acc;   // ds_write_b128, 2-way bank aliasing (free)

    // Wave-64 shuffle reduction of ssq, one slot per wave
    #pragma unroll
    for (int off = 32; off > 0; off >>= 1)
        ssq += __shfl_down(ssq, off);
    if ((t & 63) == 0) lds_ssq[t >> 6] = ssq;

    __syncthreads();

    // Threads 0..127: combine 8 rowgroups for their d, plain store
    if (t < D) {
        const float* lds_f = (const float*)lds_s4;
        float sd = 0.f;
        #pragma unroll
        for (int r = 0; r < 8; ++r) sd += lds_f[r * D + t];  // bank = t%32, conflict-free
        P[blockIdx.x * D + t] = sd;
    }
    if (t == 0) {
        SS[blockIdx.x] = lds_ssq[0] + lds_ssq[1] + lds_ssq[2] + lds_ssq[3];
    }
}

// Kernel 2: one block, 1024 threads. s[b,d] = sum_k P[(b*64+k)*D + d];
// accumulate sum(s^2) and sum(SS), finalize.
#define BLOCKS_PER_B (N / ROWS_PER_BLOCK)   // 64
__global__ __launch_bounds__(1024) void finalize_kernel(
    const float* __restrict__ P,
    const float* __restrict__ SS,
    float* __restrict__ out)
{
    __shared__ float l1[16], l2[16];
    const int t = threadIdx.x;

    float acc_s2 = 0.f;
    // 4096 (b,d) pairs, 4 per thread
    #pragma unroll
    for (int pp = 0; pp < 4; ++pp) {
        const int p = t + pp * 1024;
        const int b = p >> 7;      // p / D
        const int d = p & (D - 1);
        float s = 0.f;
        #pragma unroll 8
        for (int k = 0; k < BLOCKS_PER_B; ++k)
            s += P[(b * BLOCKS_PER_B + k) * D + d];
        acc_s2 += s * s;
    }

    float acc_ssq = 0.f;
    #pragma unroll
    for (int pp = 0; pp < 2; ++pp)
        acc_ssq += SS[t + pp * 1024];

    #pragma unroll
    for (int off = 32; off > 0; off >>= 1) {
        acc_s2  += __shfl_down(acc_s2, off);
        acc_ssq += __shfl_down(acc_ssq, off);
    }
    if ((t & 63) == 0) { l1[t >> 6] = acc_s2; l2[t >> 6] = acc_ssq; }
    __syncthreads();

    if (t == 0) {
        float sum_s2 = 0.f, sum_sq = 0.f;
        #pragma unroll
        for (int w = 0; w < 16; ++w) { sum_s2 += l1[w]; sum_sq += l2[w]; }
        const float total = 2.0f * (float)N * sum_sq - 2.0f * sum_s2;
        const float sep   = total / ((float)B * (float)N * (float)D);
        out[0] = expf(-SCALE_PARAM * sep);
    }
}

extern "C" void kernel_launch(void* const* d_in, const int* in_sizes, int n_in,
                              void* d_out, int out_size, void* d_ws, size_t ws_size,
                              hipStream_t stream) {
    const float* x = (const float*)d_in[0];
    float* out = (float*)d_out;

    float* P  = (float*)d_ws;          // NBLOCKS*D floats  (1 MB)
    float* SS = P + NBLOCKS * D;       // NBLOCKS floats

    partial_kernel<<<NBLOCKS, 256, 0, stream>>>(x, P, SS);
    finalize_kernel<<<1, 1024, 0, stream>>>(P, SS, out);
}

// Round 3
// 183.184 us; speedup vs baseline: 1.0681x; 1.0157x over previous
//
#include <hip/hip_runtime.h>
#include <math.h>

// Problem constants (from reference setup_inputs): keypoints [32, 8192, 128] fp32
#define B 32
#define N 8192
#define D 128
#define SCALE_PARAM 1e-9f

#define NBLOCKS 512
#define THREADS 512
#define ROWS_PER_BLOCK ((B * N) / NBLOCKS)     // 512 rows, all within one b (8192%512==0)
#define ROWGROUPS (THREADS / 32)               // 16
#define ITERS (ROWS_PER_BLOCK / ROWGROUPS)     // 32

typedef float __attribute__((ext_vector_type(4))) f32x4;

// Kernel 1: 512 blocks x 512 threads; block reduces 512 consecutive rows.
// Thread t: d-quad d4 = t&31 (float4 column), rowgroup rg = t>>5 (16 rows/iter).
// Wave w covers rowgroups {2w, 2w+1} -> each wave-load is a contiguous 1 KB block.
__global__ __launch_bounds__(THREADS) void partial_kernel(
    const float* __restrict__ x,
    float* __restrict__ P,     // [NBLOCKS][D] per-block d-sums (every slot written)
    float* __restrict__ SS)    // [NBLOCKS] per-block sum(x^2)
{
    __shared__ f32x4 lds_s4[ROWGROUPS][32];   // 8 KB: [rowgroup][d-quad]
    __shared__ float lds_ssq[THREADS / 64];   // per-wave sum(x^2)

    const int t  = threadIdx.x;
    const int d4 = t & 31;
    const int rg = t >> 5;

    const int row_base = blockIdx.x * ROWS_PER_BLOCK;
    const f32x4* __restrict__ x4 = (const f32x4*)x;

    f32x4 acc = {0.f, 0.f, 0.f, 0.f};
    float ssq = 0.f;

    #pragma unroll 8
    for (int it = 0; it < ITERS; ++it) {
        const int row = row_base + it * ROWGROUPS + rg;
        const f32x4 v = __builtin_nontemporal_load(&x4[row * (D / 4) + d4]);
        acc += v;
        ssq += v.x * v.x + v.y * v.y + v.z * v.z + v.w * v.w;
    }

    lds_s4[rg][d4] = acc;   // ds_write_b128, 2-way bank aliasing (free)

    // Wave-64 shuffle reduction of ssq, one slot per wave
    #pragma unroll
    for (int off = 32; off > 0; off >>= 1)
        ssq += __shfl_down(ssq, off);
    if ((t & 63) == 0) lds_ssq[t >> 6] = ssq;

    __syncthreads();

    // Threads 0..127: combine 16 rowgroups for their d, plain store
    if (t < D) {
        const float* lds_f = (const float*)lds_s4;
        float sd = 0.f;
        #pragma unroll
        for (int r = 0; r < ROWGROUPS; ++r) sd += lds_f[r * D + t];  // bank = t%32, conflict-free
        P[blockIdx.x * D + t] = sd;
    }
    if (t == 0) {
        float s = 0.f;
        #pragma unroll
        for (int w = 0; w < THREADS / 64; ++w) s += lds_ssq[w];
        SS[blockIdx.x] = s;
    }
}

// Kernel 2: one block, 1024 threads. s[b,d] = sum_k P[(b*16+k)*D + d];
// accumulate sum(s^2) and sum(SS), finalize.
#define BLOCKS_PER_B (NBLOCKS / B)   // 16
__global__ __launch_bounds__(1024) void finalize_kernel(
    const float* __restrict__ P,
    const float* __restrict__ SS,
    float* __restrict__ out)
{
    __shared__ float l1[16], l2[16];
    const int t = threadIdx.x;

    float acc_s2 = 0.f;
    // 4096 (b,d) pairs, 4 per thread
    #pragma unroll
    for (int pp = 0; pp < 4; ++pp) {
        const int p = t + pp * 1024;
        const int b = p >> 7;      // p / D
        const int d = p & (D - 1);
        float s = 0.f;
        #pragma unroll
        for (int k = 0; k < BLOCKS_PER_B; ++k)
            s += P[(b * BLOCKS_PER_B + k) * D + d];
        acc_s2 += s * s;
    }

    float acc_ssq = (t < NBLOCKS) ? SS[t] : 0.f;

    #pragma unroll
    for (int off = 32; off > 0; off >>= 1) {
        acc_s2  += __shfl_down(acc_s2, off);
        acc_ssq += __shfl_down(acc_ssq, off);
    }
    if ((t & 63) == 0) { l1[t >> 6] = acc_s2; l2[t >> 6] = acc_ssq; }
    __syncthreads();

    if (t == 0) {
        float sum_s2 = 0.f, sum_sq = 0.f;
        #pragma unroll
        for (int w = 0; w < 16; ++w) { sum_s2 += l1[w]; sum_sq += l2[w]; }
        const float total = 2.0f * (float)N * sum_sq - 2.0f * sum_s2;
        const float sep   = total / ((float)B * (float)N * (float)D);
        out[0] = expf(-SCALE_PARAM * sep);
    }
}

extern "C" void kernel_launch(void* const* d_in, const int* in_sizes, int n_in,
                              void* d_out, int out_size, void* d_ws, size_t ws_size,
                              hipStream_t stream) {
    const float* x = (const float*)d_in[0];
    float* out = (float*)d_out;

    float* P  = (float*)d_ws;          // NBLOCKS*D floats  (256 KB)
    float* SS = P + NBLOCKS * D;       // NBLOCKS floats    (2 KB)

    partial_kernel<<<NBLOCKS, THREADS, 0, stream>>>(x, P, SS);
    finalize_kernel<<<1, 1024, 0, stream>>>(P, SS, out);
}